// Round 1
// baseline (1120.771 us; speedup 1.0000x reference)
//
#include <hip/hip_runtime.h>
#include <cstdint>

// LlamaSmoothquantMLP on MI355X (gfx950).
//
// This round: T3+T4 counted-vmcnt pipeline (8-phase-template port) for both
// GEMMs. Quad-buffered LDS (BK=64, 128 KiB), stage tile t+3 while computing
// tile t, s_waitcnt vmcnt(8) once per K-tile (never 0 in the main loop),
// raw s_barrier (no vmcnt drain), setprio(1) around MFMA clusters (T5),
// row-pair XOR swizzle for conflict-free-ish ds_read_b128 (T2).
//
// GEMMs: A [M,K] row-major, B [N,K] row-major (K-contiguous both sides).
// MFMA: v_mfma_i32_32x32x32_i8. Fragment wiring + C/D layout inherited
// verbatim from the previously harness-verified kernel.

typedef int v4i  __attribute__((ext_vector_type(4)));
typedef int v16i __attribute__((ext_vector_type(16)));

typedef const void __attribute__((address_space(1)))* gas_ptr;
typedef void __attribute__((address_space(3)))* las_ptr;

static constexpr int M_TOT = 4096;   // B*S
static constexpr int HDIM  = 4096;
static constexpr int IDIM  = 11008;

#define MFMA_I8(a, b, c) __builtin_amdgcn_mfma_i32_32x32x32_i8((a), (b), (c), 0, 0, 0)
// Raw barrier with memory clobber: orders ds/global ops at compile time,
// does NOT drain vmcnt at runtime (unlike __syncthreads()).
#define BAR()        asm volatile("s_barrier" ::: "memory")
#define WAIT_LGKM0() asm volatile("s_waitcnt lgkmcnt(0)" ::: "memory")
#define WAIT_VM(N)   asm volatile("s_waitcnt vmcnt(" #N ")" ::: "memory")
#define SETPRIO(P)   __builtin_amdgcn_s_setprio(P)

__device__ __forceinline__ void gload16(const int8_t* g, int8_t* l) {
  __builtin_amdgcn_global_load_lds((gas_ptr)g, (las_ptr)l, 16, 0, 0);
}

// ---------------- LDS tile geometry (BK = 64 bytes per row) ----------------
// Row-pair interleaved XOR swizzle. A 16B chunk (row, c) with c in 0..3 lives
// at byte pair*128 + slot*16 where
//   pair = row>>1, slot = ((c<<1)|(row&1)) ^ (pair&7).
// Staging writes LDS linearly (global_load_lds is uniform-base + lane*16);
// the *global source* is pre-inverse-swizzled: for LDS chunk rel = pair*8+s,
//   sl = s ^ (pair&7); row = 2*pair + (sl&1); col = (sl>>1)*16.
// Read conflict check: 32 lanes reading fixed c over 32 consecutive rows hit
// each 8-slot bank-quad exactly 2x per 16-lane group (free minimum).
__device__ __forceinline__ v4i frag64(const int8_t* lds, int row, int c) {
  const int pair = row >> 1;
  const int slot = ((c << 1) | (row & 1)) ^ (pair & 7);
  return *(const v4i*)(lds + pair * 128 + slot * 16);
}

__device__ __forceinline__ void relmap(int rel, int& row, int& col) {
  const int pair = rel >> 3;
  const int sl = (rel & 7) ^ (pair & 7);
  row = pair * 2 + (sl & 1);
  col = (sl >> 1) * 16;
}

// ---------------- pack int32 -> int8, all four tensors in one dispatch ------
__device__ __forceinline__ void pack16(const int* __restrict__ src,
                                       int8_t* __restrict__ dst, int t) {
  const int4* s = (const int4*)(src) + t * 4;
  int4 v0 = s[0], v1 = s[1], v2 = s[2], v3 = s[3];
  int p0 = (v0.x & 0xff) | ((v0.y & 0xff) << 8) | ((v0.z & 0xff) << 16) | (v0.w << 24);
  int p1 = (v1.x & 0xff) | ((v1.y & 0xff) << 8) | ((v1.z & 0xff) << 16) | (v1.w << 24);
  int p2 = (v2.x & 0xff) | ((v2.y & 0xff) << 8) | ((v2.z & 0xff) << 16) | (v2.w << 24);
  int p3 = (v3.x & 0xff) | ((v3.y & 0xff) << 8) | ((v3.z & 0xff) << 16) | (v3.w << 24);
  ((int4*)dst)[t] = make_int4(p0, p1, p2, p3);
}

static constexpr int CX = (M_TOT * HDIM) / 16;            // 1,048,576
static constexpr int CW = (IDIM * HDIM) / 16;             // 2,818,048
static constexpr int CTOT = CX + 3 * CW;                  // 9,502,720

__global__ __launch_bounds__(256) void k_pack_all(
    const int* __restrict__ X32, const int* __restrict__ Wg32,
    const int* __restrict__ Wu32, const int* __restrict__ Wd32,
    int8_t* __restrict__ Xp, int8_t* __restrict__ Wgp,
    int8_t* __restrict__ Wup, int8_t* __restrict__ Wdp) {
  int t = blockIdx.x * blockDim.x + threadIdx.x;
  if (t >= CTOT) return;
  if (t < CX)               { pack16(X32,  Xp,  t); return; }
  t -= CX;
  if (t < CW)               { pack16(Wg32, Wgp, t); return; }
  t -= CW;
  if (t < CW)               { pack16(Wu32, Wup, t); return; }
  t -= CW;
  pack16(Wd32, Wdp, t);
}

// ---------------- gate+up fused GEMM ----------------
// Block 256M x 128N, BK=64, 8 waves (2M x 4N), wave tile 128M x 32N.
// LDS buffer (32 KiB): A [0,16K) 256 rows, G [16K,24K) 128 rows, U [24K,32K).
// Quad-buffered = 128 KiB. Staging = 4 global_load_lds/thread per K-tile.
__global__ __launch_bounds__(512, 2) void k_gateup(
    const int8_t* __restrict__ X,
    const int8_t* __restrict__ Wg,
    const int8_t* __restrict__ Wu,
    const float* __restrict__ gate_a, const float* __restrict__ gate_b,
    const float* __restrict__ up_a,   const float* __restrict__ up_b,
    const float* __restrict__ down_scale,
    int8_t* __restrict__ Q) {
  __shared__ __align__(16) int8_t lds8[4 * 32768];

  const int tid  = threadIdx.x;
  const int lane = tid & 63;
  const int wave = tid >> 6;
  const int wm   = wave >> 2;       // 0..1 : M half (128 rows)
  const int wn   = wave & 3;        // 0..3 : N quarter (32 cols)
  const int half = lane >> 5;
  const int ln31 = lane & 31;

  // bijective XCD swizzle (nwg = 1376, 1376 % 8 == 0)
  const int NB  = IDIM / 128;                    // 86
  const int NWG = (M_TOT / 256) * NB;            // 1376
  const int id  = blockIdx.x;
  const int swz = (id & 7) * (NWG >> 3) + (id >> 3);
  const int m0  = (swz / NB) * 256;
  const int n0  = (swz % NB) * 128;

  const int8_t* Ab = X  + (size_t)m0 * HDIM;
  const int8_t* Gb = Wg + (size_t)n0 * HDIM;
  const int8_t* Ub = Wu + (size_t)n0 * HDIM;

  // per-thread staging source offsets (inverse-swizzled)
  int r0, c0, r1, c1;
  relmap(tid, r0, c0);
  relmap(tid + 512, r1, c1);
  const size_t offA0 = (size_t)r0 * HDIM + c0;   // A rows 0..255 (rel tid, tid+512)
  const size_t offA1 = (size_t)r1 * HDIM + c1;
  const size_t offW  = offA0;                    // G/U rows 0..127 (rel = tid)
  const int ldsA0 = tid * 16;
  const int ldsA1 = (tid + 512) * 16;
  const int ldsG  = 16384 + tid * 16;
  const int ldsU  = 24576 + tid * 16;

  v16i accG[4], accU[4];
#pragma unroll
  for (int i = 0; i < 4; ++i)
#pragma unroll
    for (int e = 0; e < 16; ++e) { accG[i][e] = 0; accU[i][e] = 0; }

  const int rA = wm * 128 + ln31;
  const int rB = wn * 32 + ln31;

  // prologue: stage tiles 0,1,2 (12 loads); wait tile 0 (allow 8 in flight)
#pragma unroll
  for (int pt = 0; pt < 3; ++pt) {
    int8_t* sb = &lds8[pt * 32768];
    const size_t ks = (size_t)pt * 64;
    gload16(Ab + ks + offA0, sb + ldsA0);
    gload16(Ab + ks + offA1, sb + ldsA1);
    gload16(Gb + ks + offW,  sb + ldsG);
    gload16(Ub + ks + offW,  sb + ldsU);
  }
  WAIT_VM(8);
  BAR();

  const int NT = HDIM / 64;  // 64 K-tiles
  for (int t = 0; t < NT; ++t) {
    const int8_t* bufA = &lds8[(t & 3) * 32768];
    const int8_t* bufG = bufA + 16384;
    const int8_t* bufU = bufA + 24576;
    int8_t* sb = &lds8[((t + 3) & 3) * 32768];
    const size_t ks = (size_t)(t + 3) * 64;
    const bool st = (t + 3 < NT);

    // ---- phase 0: K bytes [0,32) of tile; stage A of tile t+3 ----
    {
      v4i a0 = frag64(bufA, rA,      half);
      v4i a1 = frag64(bufA, rA + 32, half);
      v4i a2 = frag64(bufA, rA + 64, half);
      v4i a3 = frag64(bufA, rA + 96, half);
      v4i gg = frag64(bufG, rB, half);
      v4i uu = frag64(bufU, rB, half);
      if (st) {
        gload16(Ab + ks + offA0, sb + ldsA0);
        gload16(Ab + ks + offA1, sb + ldsA1);
      }
      BAR();
      WAIT_LGKM0();
      SETPRIO(1);
      accG[0] = MFMA_I8(a0, gg, accG[0]);
      accU[0] = MFMA_I8(a0, uu, accU[0]);
      accG[1] = MFMA_I8(a1, gg, accG[1]);
      accU[1] = MFMA_I8(a1, uu, accU[1]);
      accG[2] = MFMA_I8(a2, gg, accG[2]);
      accU[2] = MFMA_I8(a2, uu, accU[2]);
      accG[3] = MFMA_I8(a3, gg, accG[3]);
      accU[3] = MFMA_I8(a3, uu, accU[3]);
      SETPRIO(0);
      BAR();
    }
    // ---- phase 1: K bytes [32,64); stage G,U of tile t+3; counted vmcnt ----
    {
      v4i a0 = frag64(bufA, rA,      2 + half);
      v4i a1 = frag64(bufA, rA + 32, 2 + half);
      v4i a2 = frag64(bufA, rA + 64, 2 + half);
      v4i a3 = frag64(bufA, rA + 96, 2 + half);
      v4i gg = frag64(bufG, rB, 2 + half);
      v4i uu = frag64(bufU, rB, 2 + half);
      if (st) {
        gload16(Gb + ks + offW, sb + ldsG);
        gload16(Ub + ks + offW, sb + ldsU);
      }
      BAR();
      WAIT_LGKM0();
      SETPRIO(1);
      accG[0] = MFMA_I8(a0, gg, accG[0]);
      accU[0] = MFMA_I8(a0, uu, accU[0]);
      accG[1] = MFMA_I8(a1, gg, accG[1]);
      accU[1] = MFMA_I8(a1, uu, accU[1]);
      accG[2] = MFMA_I8(a2, gg, accG[2]);
      accU[2] = MFMA_I8(a2, uu, accU[2]);
      accG[3] = MFMA_I8(a3, gg, accG[3]);
      accU[3] = MFMA_I8(a3, uu, accU[3]);
      SETPRIO(0);
      // end-of-tile: ensure tile t+1 staged; allow t+2,t+3 (8 loads) in flight
      if (t + 3 < NT)      { WAIT_VM(8); }
      else if (t + 2 < NT) { WAIT_VM(4); }
      else if (t + 1 < NT) { WAIT_VM(0); }
      BAR();
    }
  }

  const float ga = gate_a[0];
  const float ua = up_a[0];
  const float inv_ds = 1.0f / down_scale[0];
  const int n = n0 + wn * 32 + ln31;
  const float gb = gate_b[n];
  const float ub = up_b[n];

#pragma unroll
  for (int tm = 0; tm < 4; ++tm) {
#pragma unroll
    for (int r = 0; r < 16; ++r) {
      // C/D layout (m74/m101): col=lane&31, row=(r&3)+8*(r>>2)+4*(lane>>5)
      const int row_l = (r & 3) + 8 * (r >> 2) + 4 * half;
      const int m = m0 + wm * 128 + tm * 32 + row_l;
      const float g = (float)accG[tm][r] * ga + gb;
      const float u = (float)accU[tm][r] * ua + ub;
      const float sg = g / (1.0f + __expf(-g));
      const float inter = sg * u;
      float qf = rintf(inter * inv_ds);
      qf = fminf(127.0f, fmaxf(-128.0f, qf));
      Q[(size_t)m * IDIM + n] = (int8_t)qf;
    }
  }
}

// ---------------- down GEMM ----------------
// Block 256M x 256N, BK=64, 8 waves (2M x 4N), wave tile 128M x 64N.
// LDS buffer (32 KiB): A [0,16K) 256 rows, B [16K,32K) 256 rows. Quad = 128K.
// Grid = 16x16 = 256 blocks = exactly 1/CU.
__global__ __launch_bounds__(512, 2) void k_down(
    const int8_t* __restrict__ Qm,
    const int8_t* __restrict__ Wd,
    const float* __restrict__ down_a, const float* __restrict__ down_b,
    float* __restrict__ Out) {
  __shared__ __align__(16) int8_t lds8[4 * 32768];

  const int tid  = threadIdx.x;
  const int lane = tid & 63;
  const int wave = tid >> 6;
  const int wm   = wave >> 2;       // 0..1 : M half (128 rows)
  const int wn   = wave & 3;        // 0..3 : N quarter (64 cols)
  const int half = lane >> 5;
  const int ln31 = lane & 31;

  const int id  = blockIdx.x;                 // 256 blocks
  const int swz = (id & 7) * 32 + (id >> 3);  // bijective XCD swizzle
  const int m0  = (swz >> 4) * 256;
  const int n0  = (swz & 15) * 256;

  const int8_t* Ab = Qm + (size_t)m0 * IDIM;
  const int8_t* Bb = Wd + (size_t)n0 * IDIM;

  int r0, c0, r1, c1;
  relmap(tid, r0, c0);
  relmap(tid + 512, r1, c1);
  const size_t off0 = (size_t)r0 * IDIM + c0;
  const size_t off1 = (size_t)r1 * IDIM + c1;
  const int ldsA0 = tid * 16;
  const int ldsA1 = (tid + 512) * 16;
  const int ldsB0 = 16384 + tid * 16;
  const int ldsB1 = 16384 + (tid + 512) * 16;

  v16i acc[4][2];
#pragma unroll
  for (int i = 0; i < 4; ++i)
#pragma unroll
    for (int j = 0; j < 2; ++j)
#pragma unroll
      for (int e = 0; e < 16; ++e) acc[i][j][e] = 0;

  const int rA = wm * 128 + ln31;
  const int rB = wn * 64 + ln31;

#pragma unroll
  for (int pt = 0; pt < 3; ++pt) {
    int8_t* sb = &lds8[pt * 32768];
    const size_t ks = (size_t)pt * 64;
    gload16(Ab + ks + off0, sb + ldsA0);
    gload16(Ab + ks + off1, sb + ldsA1);
    gload16(Bb + ks + off0, sb + ldsB0);
    gload16(Bb + ks + off1, sb + ldsB1);
  }
  WAIT_VM(8);
  BAR();

  const int NT = IDIM / 64;  // 172 K-tiles
  for (int t = 0; t < NT; ++t) {
    const int8_t* bufA = &lds8[(t & 3) * 32768];
    const int8_t* bufB = bufA + 16384;
    int8_t* sb = &lds8[((t + 3) & 3) * 32768];
    const size_t ks = (size_t)(t + 3) * 64;
    const bool st = (t + 3 < NT);

    // ---- phase 0 ----
    {
      v4i a0 = frag64(bufA, rA,      half);
      v4i a1 = frag64(bufA, rA + 32, half);
      v4i a2 = frag64(bufA, rA + 64, half);
      v4i a3 = frag64(bufA, rA + 96, half);
      v4i b0 = frag64(bufB, rB,      half);
      v4i b1 = frag64(bufB, rB + 32, half);
      if (st) {
        gload16(Ab + ks + off0, sb + ldsA0);
        gload16(Ab + ks + off1, sb + ldsA1);
      }
      BAR();
      WAIT_LGKM0();
      SETPRIO(1);
      acc[0][0] = MFMA_I8(a0, b0, acc[0][0]);
      acc[0][1] = MFMA_I8(a0, b1, acc[0][1]);
      acc[1][0] = MFMA_I8(a1, b0, acc[1][0]);
      acc[1][1] = MFMA_I8(a1, b1, acc[1][1]);
      acc[2][0] = MFMA_I8(a2, b0, acc[2][0]);
      acc[2][1] = MFMA_I8(a2, b1, acc[2][1]);
      acc[3][0] = MFMA_I8(a3, b0, acc[3][0]);
      acc[3][1] = MFMA_I8(a3, b1, acc[3][1]);
      SETPRIO(0);
      BAR();
    }
    // ---- phase 1 ----
    {
      v4i a0 = frag64(bufA, rA,      2 + half);
      v4i a1 = frag64(bufA, rA + 32, 2 + half);
      v4i a2 = frag64(bufA, rA + 64, 2 + half);
      v4i a3 = frag64(bufA, rA + 96, 2 + half);
      v4i b0 = frag64(bufB, rB,      2 + half);
      v4i b1 = frag64(bufB, rB + 32, 2 + half);
      if (st) {
        gload16(Bb + ks + off0, sb + ldsB0);
        gload16(Bb + ks + off1, sb + ldsB1);
      }
      BAR();
      WAIT_LGKM0();
      SETPRIO(1);
      acc[0][0] = MFMA_I8(a0, b0, acc[0][0]);
      acc[0][1] = MFMA_I8(a0, b1, acc[0][1]);
      acc[1][0] = MFMA_I8(a1, b0, acc[1][0]);
      acc[1][1] = MFMA_I8(a1, b1, acc[1][1]);
      acc[2][0] = MFMA_I8(a2, b0, acc[2][0]);
      acc[2][1] = MFMA_I8(a2, b1, acc[2][1]);
      acc[3][0] = MFMA_I8(a3, b0, acc[3][0]);
      acc[3][1] = MFMA_I8(a3, b1, acc[3][1]);
      SETPRIO(0);
      if (t + 3 < NT)      { WAIT_VM(8); }
      else if (t + 2 < NT) { WAIT_VM(4); }
      else if (t + 1 < NT) { WAIT_VM(0); }
      BAR();
    }
  }

  const float da = down_a[0];
#pragma unroll
  for (int tn = 0; tn < 2; ++tn) {
    const int n = n0 + wn * 64 + tn * 32 + ln31;
    const float db = down_b[n];
#pragma unroll
    for (int tm = 0; tm < 4; ++tm) {
#pragma unroll
      for (int r = 0; r < 16; ++r) {
        const int row_l = (r & 3) + 8 * (r >> 2) + 4 * half;
        const int m = m0 + wm * 128 + tm * 32 + row_l;
        Out[(size_t)m * HDIM + n] = (float)acc[tm][tn][r] * da + db;
      }
    }
  }
}

extern "C" void kernel_launch(void* const* d_in, const int* in_sizes, int n_in,
                              void* d_out, int out_size, void* d_ws, size_t ws_size,
                              hipStream_t stream) {
  const int* X32        = (const int*)d_in[0];
  const int* Wg32       = (const int*)d_in[1];
  const int* Wu32       = (const int*)d_in[2];
  const int* Wd32       = (const int*)d_in[3];
  const float* gate_a   = (const float*)d_in[4];
  const float* gate_b   = (const float*)d_in[5];
  const float* up_a     = (const float*)d_in[6];
  const float* up_b     = (const float*)d_in[7];
  const float* down_a   = (const float*)d_in[8];
  const float* down_b   = (const float*)d_in[9];
  const float* down_scale = (const float*)d_in[10];
  float* Out = (float*)d_out;

  const size_t nX = (size_t)M_TOT * HDIM;
  const size_t nW = (size_t)IDIM * HDIM;

  // Workspace: Q | Xp | Wgp | Wup | Wdp  (~197 MB)
  int8_t* Q   = (int8_t*)d_ws;
  int8_t* Xp  = Q   + nW;
  int8_t* Wgp = Xp  + nX;
  int8_t* Wup = Wgp + nW;
  int8_t* Wdp = Wup + nW;

  k_pack_all<<<(CTOT + 255) / 256, 256, 0, stream>>>(X32, Wg32, Wu32, Wd32,
                                                     Xp, Wgp, Wup, Wdp);

  k_gateup<<<dim3((M_TOT / 256) * (IDIM / 128)), dim3(512), 0, stream>>>(
      Xp, Wgp, Wup, gate_a, gate_b, up_a, up_b, down_scale, Q);

  k_down<<<dim3((M_TOT / 256) * (HDIM / 256)), dim3(512), 0, stream>>>(
      Q, Wdp, down_a, down_b, Out);
}

// Round 2
// 1091.599 us; speedup vs baseline: 1.0267x; 1.0267x over previous
//
#include <hip/hip_runtime.h>
#include <cstdint>

// LlamaSmoothquantMLP on MI355X (gfx950).
//
// Round 2: BK=128 double-buffered tiles (full 128-byte-line staging fixes the
// 2x read over-fetch that BK=64 caused), ONE barrier + one vmcnt(0) publish
// per K-tile (loads have a full tile of flight -> drain is covered), 32-MFMA
// clusters with compiler-interleaved ds_read_b128 (fine-grained lgkmcnt),
// setprio(1) around the compute cluster, zero-conflict pair-XOR LDS swizzle
// (16-slot variant of the round-1 layout that measured SQ_LDS_BANK_CONFLICT=0).
//
// GEMMs: A [M,K] row-major, B [N,K] row-major (K-contiguous both sides).
// MFMA: v_mfma_i32_32x32x32_i8. C/D layout m74/m101 (verified previously).

typedef int v4i  __attribute__((ext_vector_type(4)));
typedef int v16i __attribute__((ext_vector_type(16)));

typedef const void __attribute__((address_space(1)))* gas_ptr;
typedef void __attribute__((address_space(3)))* las_ptr;

static constexpr int M_TOT = 4096;   // B*S
static constexpr int HDIM  = 4096;
static constexpr int IDIM  = 11008;

#define MFMA_I8(a, b, c) __builtin_amdgcn_mfma_i32_32x32x32_i8((a), (b), (c), 0, 0, 0)
// Raw barrier: compile-time memory order, no runtime vmcnt drain.
#define BAR()      asm volatile("s_barrier" ::: "memory")
#define WAIT_VM0() asm volatile("s_waitcnt vmcnt(0)" ::: "memory")
#define SETPRIO(P) __builtin_amdgcn_s_setprio(P)

__device__ __forceinline__ void gload16(const int8_t* g, int8_t* l) {
  __builtin_amdgcn_global_load_lds((gas_ptr)g, (las_ptr)l, 16, 0, 0);
}

// ---------------- LDS tile geometry (BK = 128 bytes per row) ----------------
// Row-pair interleaved XOR swizzle, 16 slots of 16B per 256B row-pair line.
// Chunk (row, c) c=0..7 lives at byte  pair*256 + slot*16,
//   pair = row>>1, slot = ((c<<1)|(row&1)) ^ (pair&15).
// Staging writes LDS linearly (global_load_lds dest = base + lane*16); the
// *global source* is pre-inverse-swizzled. A wave's 64 consecutive chunks =
// 4 pairs = 8 FULL 128B rows -> every fetch is whole cache lines (HDIM and
// IDIM are both multiples of 128, so rows are 128B-aligned).
// Read side: 32 lanes, fixed c, 32 consecutive rows -> 4 lanes per bank-quad,
// same distribution as the round-1 layout that measured 0 conflicts.
__device__ __forceinline__ v4i frag128(const int8_t* lds, int row, int c) {
  const int pair = row >> 1;
  const int slot = ((c << 1) | (row & 1)) ^ (pair & 15);
  return *(const v4i*)(lds + pair * 256 + slot * 16);
}

// Inverse map for staging: LDS chunk index rel -> (row, col) in the tile.
__device__ __forceinline__ void relmap128(int rel, int& row, int& col) {
  const int pair = rel >> 4;
  const int sl = (rel & 15) ^ (pair & 15);
  row = 2 * pair + (sl & 1);
  col = (sl >> 1) * 16;
}

// ---------------- pack int32 -> int8, all four tensors in one dispatch ------
__device__ __forceinline__ void pack16(const int* __restrict__ src,
                                       int8_t* __restrict__ dst, int t) {
  const int4* s = (const int4*)(src) + t * 4;
  int4 v0 = s[0], v1 = s[1], v2 = s[2], v3 = s[3];
  int p0 = (v0.x & 0xff) | ((v0.y & 0xff) << 8) | ((v0.z & 0xff) << 16) | (v0.w << 24);
  int p1 = (v1.x & 0xff) | ((v1.y & 0xff) << 8) | ((v1.z & 0xff) << 16) | (v1.w << 24);
  int p2 = (v2.x & 0xff) | ((v2.y & 0xff) << 8) | ((v2.z & 0xff) << 16) | (v2.w << 24);
  int p3 = (v3.x & 0xff) | ((v3.y & 0xff) << 8) | ((v3.z & 0xff) << 16) | (v3.w << 24);
  ((int4*)dst)[t] = make_int4(p0, p1, p2, p3);
}

static constexpr int CX = (M_TOT * HDIM) / 16;            // 1,048,576
static constexpr int CW = (IDIM * HDIM) / 16;             // 2,818,048
static constexpr int CTOT = CX + 3 * CW;                  // 9,502,720

__global__ __launch_bounds__(256) void k_pack_all(
    const int* __restrict__ X32, const int* __restrict__ Wg32,
    const int* __restrict__ Wu32, const int* __restrict__ Wd32,
    int8_t* __restrict__ Xp, int8_t* __restrict__ Wgp,
    int8_t* __restrict__ Wup, int8_t* __restrict__ Wdp) {
  int t = blockIdx.x * blockDim.x + threadIdx.x;
  if (t >= CTOT) return;
  if (t < CX)               { pack16(X32,  Xp,  t); return; }
  t -= CX;
  if (t < CW)               { pack16(Wg32, Wgp, t); return; }
  t -= CW;
  if (t < CW)               { pack16(Wu32, Wup, t); return; }
  t -= CW;
  pack16(Wd32, Wdp, t);
}

// ---------------- gate+up fused GEMM ----------------
// Block 256M x 128N, BK=128, 8 waves (2M x 4N), wave tile 128M x 32N.
// LDS buffer 64 KiB: A [0,32K) 256 rows, G [32K,48K) 128 rows, U [48K,64K).
// Double-buffered = 128 KiB -> 1 block/CU, 8 waves.
// Per tile: stage next (8 gloads) -> 24 ds_read_b128 + 32 MFMA -> vm(0)+bar.
__global__ __launch_bounds__(512, 2) void k_gateup(
    const int8_t* __restrict__ X,
    const int8_t* __restrict__ Wg,
    const int8_t* __restrict__ Wu,
    const float* __restrict__ gate_a, const float* __restrict__ gate_b,
    const float* __restrict__ up_a,   const float* __restrict__ up_b,
    const float* __restrict__ down_scale,
    int8_t* __restrict__ Q) {
  __shared__ __align__(16) int8_t lds8[2 * 65536];

  const int tid  = threadIdx.x;
  const int lane = tid & 63;
  const int wave = tid >> 6;
  const int wm   = wave >> 2;       // 0..1 : M half (128 rows)
  const int wn   = wave & 3;        // 0..3 : N quarter (32 cols)
  const int half = lane >> 5;
  const int ln31 = lane & 31;

  // plain 2D grid, x (M) fastest: 16 consecutive blocks share the weight
  // panels (n0 fixed) -> L2/L3 friendly (round-0's proven order).
  const int m0 = blockIdx.x * 256;
  const int n0 = blockIdx.y * 128;

  const int8_t* Ab = X  + (size_t)m0 * HDIM;
  const int8_t* Gb = Wg + (size_t)n0 * HDIM;
  const int8_t* Ub = Wu + (size_t)n0 * HDIM;

  // per-thread inverse-swizzled global source offsets
  int r0, c0, r1, c1, r2, c2, r3, c3;
  relmap128(tid,        r0, c0);
  relmap128(tid + 512,  r1, c1);
  relmap128(tid + 1024, r2, c2);
  relmap128(tid + 1536, r3, c3);
  const size_t oA0 = (size_t)r0 * HDIM + c0;
  const size_t oA1 = (size_t)r1 * HDIM + c1;
  const size_t oA2 = (size_t)r2 * HDIM + c2;
  const size_t oA3 = (size_t)r3 * HDIM + c3;

  v16i accG[4], accU[4];
#pragma unroll
  for (int i = 0; i < 4; ++i)
#pragma unroll
    for (int e = 0; e < 16; ++e) { accG[i][e] = 0; accU[i][e] = 0; }

  const int rA = wm * 128 + ln31;
  const int rB = wn * 32 + ln31;

  // prologue: stage tile 0, publish.
  {
    int8_t* sb = lds8;
    gload16(Ab + oA0, sb + tid * 16);
    gload16(Ab + oA1, sb + (tid + 512) * 16);
    gload16(Ab + oA2, sb + (tid + 1024) * 16);
    gload16(Ab + oA3, sb + (tid + 1536) * 16);
    gload16(Gb + oA0, sb + 32768 + tid * 16);
    gload16(Gb + oA1, sb + 32768 + (tid + 512) * 16);
    gload16(Ub + oA0, sb + 49152 + tid * 16);
    gload16(Ub + oA1, sb + 49152 + (tid + 512) * 16);
    WAIT_VM0();
    BAR();
  }

  const int NT = HDIM / 128;  // 32 K-tiles
  for (int s = 0; s < NT; ++s) {
    const int8_t* bufA = lds8 + (s & 1) * 65536;
    const int8_t* bufG = bufA + 32768;
    const int8_t* bufU = bufA + 49152;

    if (s + 1 < NT) {
      int8_t* sb = lds8 + ((s + 1) & 1) * 65536;
      const int8_t* ap = Ab + (size_t)(s + 1) * 128;
      const int8_t* gp = Gb + (size_t)(s + 1) * 128;
      const int8_t* up = Ub + (size_t)(s + 1) * 128;
      gload16(ap + oA0, sb + tid * 16);
      gload16(ap + oA1, sb + (tid + 512) * 16);
      gload16(ap + oA2, sb + (tid + 1024) * 16);
      gload16(ap + oA3, sb + (tid + 1536) * 16);
      gload16(gp + oA0, sb + 32768 + tid * 16);
      gload16(gp + oA1, sb + 32768 + (tid + 512) * 16);
      gload16(up + oA0, sb + 49152 + tid * 16);
      gload16(up + oA1, sb + 49152 + (tid + 512) * 16);
    }

    SETPRIO(1);
#pragma unroll
    for (int ks = 0; ks < 4; ++ks) {
      const int c = 2 * ks + half;
      v4i a0 = frag128(bufA, rA,      c);
      v4i a1 = frag128(bufA, rA + 32, c);
      v4i a2 = frag128(bufA, rA + 64, c);
      v4i a3 = frag128(bufA, rA + 96, c);
      v4i gg = frag128(bufG, rB, c);
      v4i uu = frag128(bufU, rB, c);
      accG[0] = MFMA_I8(a0, gg, accG[0]);
      accU[0] = MFMA_I8(a0, uu, accU[0]);
      accG[1] = MFMA_I8(a1, gg, accG[1]);
      accU[1] = MFMA_I8(a1, uu, accU[1]);
      accG[2] = MFMA_I8(a2, gg, accG[2]);
      accU[2] = MFMA_I8(a2, uu, accU[2]);
      accG[3] = MFMA_I8(a3, gg, accG[3]);
      accU[3] = MFMA_I8(a3, uu, accU[3]);
    }
    SETPRIO(0);

    if (s + 1 < NT) {
      WAIT_VM0();   // publish tile s+1 (its loads flew for the whole tile)
      BAR();        // all waves' reads of buffer (s+1)&1 are consumed
    }
  }

  const float ga = gate_a[0];
  const float ua = up_a[0];
  const float inv_ds = 1.0f / down_scale[0];
  const int n = n0 + wn * 32 + ln31;
  const float gb = gate_b[n];
  const float ub = up_b[n];

#pragma unroll
  for (int tm = 0; tm < 4; ++tm) {
#pragma unroll
    for (int r = 0; r < 16; ++r) {
      // C/D layout (m74/m101): col=lane&31, row=(r&3)+8*(r>>2)+4*(lane>>5)
      const int row_l = (r & 3) + 8 * (r >> 2) + 4 * half;
      const int m = m0 + wm * 128 + tm * 32 + row_l;
      const float g = (float)accG[tm][r] * ga + gb;
      const float u = (float)accU[tm][r] * ua + ub;
      const float sg = g / (1.0f + __expf(-g));
      const float inter = sg * u;
      float qf = rintf(inter * inv_ds);
      qf = fminf(127.0f, fmaxf(-128.0f, qf));
      Q[(size_t)m * IDIM + n] = (int8_t)qf;
    }
  }
}

// ---------------- down GEMM ----------------
// Block 256M x 256N, BK=128, 8 waves (2M x 4N), wave tile 128M x 64N.
// LDS buffer 64 KiB: A [0,32K) 256 rows, B [32K,64K) 256 rows. Double = 128K.
// Grid 16x16 = 256 blocks = exactly 1/CU. Same pipeline as k_gateup.
__global__ __launch_bounds__(512, 2) void k_down(
    const int8_t* __restrict__ Qm,
    const int8_t* __restrict__ Wd,
    const float* __restrict__ down_a, const float* __restrict__ down_b,
    float* __restrict__ Out) {
  __shared__ __align__(16) int8_t lds8[2 * 65536];

  const int tid  = threadIdx.x;
  const int lane = tid & 63;
  const int wave = tid >> 6;
  const int wm   = wave >> 2;       // 0..1 : M half (128 rows)
  const int wn   = wave & 3;        // 0..3 : N quarter (64 cols)
  const int half = lane >> 5;
  const int ln31 = lane & 31;

  const int m0 = blockIdx.x * 256;
  const int n0 = blockIdx.y * 256;

  const int8_t* Ab = Qm + (size_t)m0 * IDIM;
  const int8_t* Bb = Wd + (size_t)n0 * IDIM;

  int r0, c0, r1, c1, r2, c2, r3, c3;
  relmap128(tid,        r0, c0);
  relmap128(tid + 512,  r1, c1);
  relmap128(tid + 1024, r2, c2);
  relmap128(tid + 1536, r3, c3);
  const size_t o0 = (size_t)r0 * IDIM + c0;
  const size_t o1 = (size_t)r1 * IDIM + c1;
  const size_t o2 = (size_t)r2 * IDIM + c2;
  const size_t o3 = (size_t)r3 * IDIM + c3;

  v16i acc[4][2];
#pragma unroll
  for (int i = 0; i < 4; ++i)
#pragma unroll
    for (int j = 0; j < 2; ++j)
#pragma unroll
      for (int e = 0; e < 16; ++e) acc[i][j][e] = 0;

  const int rA = wm * 128 + ln31;
  const int rB = wn * 64 + ln31;

  // prologue: stage tile 0, publish.
  {
    int8_t* sb = lds8;
    gload16(Ab + o0, sb + tid * 16);
    gload16(Ab + o1, sb + (tid + 512) * 16);
    gload16(Ab + o2, sb + (tid + 1024) * 16);
    gload16(Ab + o3, sb + (tid + 1536) * 16);
    gload16(Bb + o0, sb + 32768 + tid * 16);
    gload16(Bb + o1, sb + 32768 + (tid + 512) * 16);
    gload16(Bb + o2, sb + 32768 + (tid + 1024) * 16);
    gload16(Bb + o3, sb + 32768 + (tid + 1536) * 16);
    WAIT_VM0();
    BAR();
  }

  const int NT = IDIM / 128;  // 86 K-tiles
  for (int s = 0; s < NT; ++s) {
    const int8_t* bufA = lds8 + (s & 1) * 65536;
    const int8_t* bufB = bufA + 32768;

    if (s + 1 < NT) {
      int8_t* sb = lds8 + ((s + 1) & 1) * 65536;
      const int8_t* ap = Ab + (size_t)(s + 1) * 128;
      const int8_t* bp = Bb + (size_t)(s + 1) * 128;
      gload16(ap + o0, sb + tid * 16);
      gload16(ap + o1, sb + (tid + 512) * 16);
      gload16(ap + o2, sb + (tid + 1024) * 16);
      gload16(ap + o3, sb + (tid + 1536) * 16);
      gload16(bp + o0, sb + 32768 + tid * 16);
      gload16(bp + o1, sb + 32768 + (tid + 512) * 16);
      gload16(bp + o2, sb + 32768 + (tid + 1024) * 16);
      gload16(bp + o3, sb + 32768 + (tid + 1536) * 16);
    }

    SETPRIO(1);
#pragma unroll
    for (int ks = 0; ks < 4; ++ks) {
      const int c = 2 * ks + half;
      v4i a0 = frag128(bufA, rA,      c);
      v4i a1 = frag128(bufA, rA + 32, c);
      v4i a2 = frag128(bufA, rA + 64, c);
      v4i a3 = frag128(bufA, rA + 96, c);
      v4i b0 = frag128(bufB, rB,      c);
      v4i b1 = frag128(bufB, rB + 32, c);
      acc[0][0] = MFMA_I8(a0, b0, acc[0][0]);
      acc[0][1] = MFMA_I8(a0, b1, acc[0][1]);
      acc[1][0] = MFMA_I8(a1, b0, acc[1][0]);
      acc[1][1] = MFMA_I8(a1, b1, acc[1][1]);
      acc[2][0] = MFMA_I8(a2, b0, acc[2][0]);
      acc[2][1] = MFMA_I8(a2, b1, acc[2][1]);
      acc[3][0] = MFMA_I8(a3, b0, acc[3][0]);
      acc[3][1] = MFMA_I8(a3, b1, acc[3][1]);
    }
    SETPRIO(0);

    if (s + 1 < NT) {
      WAIT_VM0();
      BAR();
    }
  }

  const float da = down_a[0];
#pragma unroll
  for (int tn = 0; tn < 2; ++tn) {
    const int n = n0 + wn * 64 + tn * 32 + ln31;
    const float db = down_b[n];
#pragma unroll
    for (int tm = 0; tm < 4; ++tm) {
#pragma unroll
      for (int r = 0; r < 16; ++r) {
        const int row_l = (r & 3) + 8 * (r >> 2) + 4 * half;
        const int m = m0 + wm * 128 + tm * 32 + row_l;
        Out[(size_t)m * HDIM + n] = (float)acc[tm][tn][r] * da + db;
      }
    }
  }
}

extern "C" void kernel_launch(void* const* d_in, const int* in_sizes, int n_in,
                              void* d_out, int out_size, void* d_ws, size_t ws_size,
                              hipStream_t stream) {
  const int* X32        = (const int*)d_in[0];
  const int* Wg32       = (const int*)d_in[1];
  const int* Wu32       = (const int*)d_in[2];
  const int* Wd32       = (const int*)d_in[3];
  const float* gate_a   = (const float*)d_in[4];
  const float* gate_b   = (const float*)d_in[5];
  const float* up_a     = (const float*)d_in[6];
  const float* up_b     = (const float*)d_in[7];
  const float* down_a   = (const float*)d_in[8];
  const float* down_b   = (const float*)d_in[9];
  const float* down_scale = (const float*)d_in[10];
  float* Out = (float*)d_out;

  const size_t nX = (size_t)M_TOT * HDIM;
  const size_t nW = (size_t)IDIM * HDIM;

  // Workspace: Q | Xp | Wgp | Wup | Wdp  (~197 MB)
  int8_t* Q   = (int8_t*)d_ws;
  int8_t* Xp  = Q   + nW;
  int8_t* Wgp = Xp  + nX;
  int8_t* Wup = Wgp + nW;
  int8_t* Wdp = Wup + nW;

  k_pack_all<<<(CTOT + 255) / 256, 256, 0, stream>>>(X32, Wg32, Wu32, Wd32,
                                                     Xp, Wgp, Wup, Wdp);

  k_gateup<<<dim3(M_TOT / 256, IDIM / 128), dim3(512), 0, stream>>>(
      Xp, Wgp, Wup, gate_a, gate_b, up_a, up_b, down_scale, Q);

  k_down<<<dim3(M_TOT / 256, HDIM / 256), dim3(512), 0, stream>>>(
      Q, Wdp, down_a, down_b, Out);
}